// Round 3
// baseline (729.382 us; speedup 1.0000x reference)
//
#include <hip/hip_runtime.h>
#include <hip/hip_bf16.h>
#include <type_traits>

// PointNetConv on MI355X (gfx950) — round 3: sort-by-destination, zero-atomic max.
//   K0 detect : sniff dtype of x (bf16 vs f32) -> flag
//   K1 zero   : deg[N] = 0
//   K2 hist   : deg[col]++ (atomicAdd, 1.6M)
//   K3 scan   : start/cursor = exclusive prefix sum of deg (1 block)
//   K4 scatter: srow[slot] = row, slot = cursor[col]++ (atomicAdd, 1.6M)
//   K5 node_gemm<T,false>: xw1b = bf16(x @ W1x + b1)   (stored in d_out as scratch)
//   K6 pernode<T>: one WAVE per destination node; chunks of 16 edges through
//                  MFMA 16x16x32; running max in registers; shfl_xor butterfly;
//                  maxbf[n] = bf16(max + b2)  (0 for empty nodes). NO atomics.
//   K7 node_gemm<T,true> : d_out = T(maxbf + x @ Wr + br)
//
// ws layout (~19.8 MB, fits the >=25.6MB proven in round 2):
//   [0)            maxbf   N*128 bf16   12.8 MB
//   [N*256)        srow    E   int       6.4 MB
//   [+E*4)         deg     N   int
//                  start   N+1 int
//                  cursor  N   int
//                  flag    1   int

typedef __bf16 bf16_t;
typedef __bf16 bf16x8 __attribute__((ext_vector_type(8)));
typedef float  f32x4  __attribute__((ext_vector_type(4)));

// --- K0: dtype sniffer (low 16-bit halves of f32 words are ~uniform; of
// bf16-pair words they are bf16 N(0,1) with exponent in [0x68,0x88]).
__global__ void detect_kernel(const unsigned* __restrict__ xw, int* __restrict__ flag) {
  int lane = threadIdx.x;            // 64 threads
  int cnt = 0;
#pragma unroll
  for (int i = 0; i < 4; ++i) {
    unsigned w = xw[lane * 4 + i];
    unsigned e = (w >> 7) & 0xFFu;
    cnt += (e >= 0x68u && e <= 0x88u) ? 1 : 0;
  }
#pragma unroll
  for (int off = 32; off > 0; off >>= 1) cnt += __shfl_down(cnt, off, 64);
  if (lane == 0) *flag = (cnt >= 128) ? 0 : 1;   // 0 = bf16, 1 = f32
}

__global__ __launch_bounds__(256) void zero_kernel(int* __restrict__ p, int n) {
  int i = blockIdx.x * 256 + threadIdx.x;
  if (i < n) p[i] = 0;
}

__global__ __launch_bounds__(256) void hist_kernel(const int* __restrict__ eidx,
                                                   int* __restrict__ deg, int E) {
  int i = blockIdx.x * 256 + threadIdx.x;
  if (i < E) atomicAdd(&deg[eidx[E + i]], 1);
}

// 1 block, 1024 threads: exclusive scan of deg -> start, cursor; start[N]=E.
__global__ __launch_bounds__(1024) void scan_kernel(const int* __restrict__ deg,
                                                    int* __restrict__ start,
                                                    int* __restrict__ cursor, int N) {
  __shared__ int wsum[16];
  __shared__ int carry_s;
  const int tid = threadIdx.x, lane = tid & 63, w = tid >> 6;
  if (tid == 0) carry_s = 0;
  __syncthreads();
  for (int base = 0; base < N; base += 1024) {
    int i = base + tid;
    int v = (i < N) ? deg[i] : 0;
    int s = v;
#pragma unroll
    for (int off = 1; off < 64; off <<= 1) {
      int t = __shfl_up(s, off, 64);
      if (lane >= off) s += t;
    }
    if (lane == 63) wsum[w] = s;
    __syncthreads();
    int wexcl = 0;
    for (int j = 0; j < w; ++j) wexcl += wsum[j];
    int excl = carry_s + wexcl + (s - v);
    if (i < N) { start[i] = excl; cursor[i] = excl; }
    __syncthreads();
    if (tid == 1023) carry_s = excl + v;
    __syncthreads();
  }
  if (tid == 0) start[N] = carry_s;
}

__global__ __launch_bounds__(256) void scatter_kernel(const int* __restrict__ eidx,
                                                      int* __restrict__ cursor,
                                                      int* __restrict__ srow, int E) {
  int i = blockIdx.x * 256 + threadIdx.x;
  if (i < E) {
    int slot = atomicAdd(&cursor[eidx[E + i]], 1);
    srow[slot] = eidx[i];
  }
}

template <typename T>
__device__ __forceinline__ bf16x8 load_frag8(const T* p) {
  bf16x8 r;
  if constexpr (std::is_same<T, float>::value) {
    float4 a = *(const float4*)p;
    float4 b = *(const float4*)(p + 4);
    r[0] = (bf16_t)a.x; r[1] = (bf16_t)a.y; r[2] = (bf16_t)a.z; r[3] = (bf16_t)a.w;
    r[4] = (bf16_t)b.x; r[5] = (bf16_t)b.y; r[6] = (bf16_t)b.z; r[7] = (bf16_t)b.w;
  } else {
    r = *(const bf16x8*)p;
  }
  return r;
}

// ---------------------------------------------------------------------------
// Node GEMM: 64 nodes/block, 16 nodes/wave, MFMA 16x16x32 bf16.
// FINAL=false: d_out scratch (bf16) = x @ W + bias
// FINAL=true : d_out(T) = maxbf + x @ W + bias
// ---------------------------------------------------------------------------
template <typename T, bool FINAL>
__global__ __launch_bounds__(256) void node_gemm_kernel(
    const T* __restrict__ xin, const T* __restrict__ W,
    const T* __restrict__ bias, const bf16_t* __restrict__ maxv,
    void* __restrict__ dst, const int* __restrict__ flag, int N)
{
  constexpr bool IS_F32 = std::is_same<T, float>::value;
  if ((*flag != 0) != IS_F32) return;

  __shared__ bf16_t ws_[8][4][64][8];  // B-fragment-major, 32 KB
  __shared__ float  bs_[128];

  const int tid = threadIdx.x;
  for (int it = tid; it < 8 * 4 * 64; it += 256) {
    int nt = it >> 8, kt = (it >> 6) & 3, l = it & 63;
    int n = nt * 16 + (l & 15), quad = l >> 4;
    bf16x8 v;
#pragma unroll
    for (int j = 0; j < 8; ++j) v[j] = (bf16_t)(float)W[(kt * 32 + quad * 8 + j) * 128 + n];
    *(bf16x8*)&ws_[nt][kt][l][0] = v;
  }
  if (tid < 128) bs_[tid] = (float)bias[tid];
  __syncthreads();

  const int w = tid >> 6, lane = tid & 63;
  const int m15 = lane & 15, quad = lane >> 4;

  int node_a = blockIdx.x * 64 + w * 16 + m15;
  const T* xrow = xin + (long)min(node_a, N - 1) * 128;
  bf16x8 a[4];
#pragma unroll
  for (int kt = 0; kt < 4; ++kt)
    a[kt] = load_frag8(xrow + kt * 32 + quad * 8);

  f32x4 acc[8];
#pragma unroll
  for (int nt = 0; nt < 8; ++nt) acc[nt] = (f32x4){0.f, 0.f, 0.f, 0.f};
#pragma unroll
  for (int nt = 0; nt < 8; ++nt)
#pragma unroll
    for (int kt = 0; kt < 4; ++kt)
      acc[nt] = __builtin_amdgcn_mfma_f32_16x16x32_bf16(
          a[kt], *(const bf16x8*)&ws_[nt][kt][lane][0], acc[nt], 0, 0, 0);

#pragma unroll
  for (int r = 0; r < 4; ++r) {
    int node = blockIdx.x * 64 + w * 16 + quad * 4 + r;
    if (node < N) {
#pragma unroll
      for (int nt = 0; nt < 8; ++nt) {
        int c = nt * 16 + m15;
        float v = acc[nt][r] + bs_[c];
        long idx = (long)node * 128 + c;
        if constexpr (FINAL) {
          v += (float)maxv[idx];
          if constexpr (IS_F32) ((float*)dst)[idx] = v;
          else                  ((bf16_t*)dst)[idx] = (bf16_t)v;
        } else {
          ((bf16_t*)dst)[idx] = (bf16_t)v;
        }
      }
    }
  }
}

// ---------------------------------------------------------------------------
// K6: one wave per destination node. Edges of node n are srow[start[n]..start[n+1]).
// Chunks of 16 edges -> MFMA; running max in registers; padding duplicates the
// last real edge (harmless for max). Result: maxbf[n] = bf16(max + b2), 0 if empty.
// ---------------------------------------------------------------------------
template <typename T>
__global__ __launch_bounds__(256) void pernode_kernel(
    const T* __restrict__ pos, const bf16_t* __restrict__ xw1b,
    const T* __restrict__ W1, const T* __restrict__ W2, const T* __restrict__ b2,
    const int* __restrict__ start, const int* __restrict__ srow,
    bf16_t* __restrict__ maxbf, const int* __restrict__ flag, int N)
{
  constexpr bool IS_F32 = std::is_same<T, float>::value;
  if ((*flag != 0) != IS_F32) return;

  __shared__ bf16_t w2s[8][4][64][8];  // 32 KB, B-fragment-major
  __shared__ float  w1ps[3][128];      // pos rows of W1 (rows 128..130)
  __shared__ float  b2s[128];

  const int tid = threadIdx.x;
  for (int it = tid; it < 8 * 4 * 64; it += 256) {
    int nt = it >> 8, kt = (it >> 6) & 3, l = it & 63;
    int ncol = nt * 16 + (l & 15), q = l >> 4;
    bf16x8 v;
#pragma unroll
    for (int j = 0; j < 8; ++j) v[j] = (bf16_t)(float)W2[(kt * 32 + q * 8 + j) * 128 + ncol];
    *(bf16x8*)&w2s[nt][kt][l][0] = v;
  }
  for (int it = tid; it < 384; it += 256) {
    int d = it >> 7, c = it & 127;
    w1ps[d][c] = (float)W1[(128 + d) * 128 + c];
  }
  if (tid < 128) b2s[tid] = (float)b2[tid];
  __syncthreads();

  const int w = tid >> 6, lane = tid & 63;
  const int m15 = lane & 15, quad = lane >> 4;

  float biasv[8];
#pragma unroll
  for (int nt = 0; nt < 8; ++nt) biasv[nt] = b2s[nt * 16 + m15];

  for (int n = blockIdx.x * 4 + w; n < N; n += gridDim.x * 4) {
    const int s = start[n], e = start[n + 1];
    if (e <= s) {                     // empty segment -> 0 (jnp.where(isneginf))
      if (quad == 0) {
#pragma unroll
        for (int nt = 0; nt < 8; ++nt)
          maxbf[(long)n * 128 + nt * 16 + m15] = (bf16_t)0.f;
      }
      continue;
    }
    const float pn0 = (float)pos[n * 3 + 0];
    const float pn1 = (float)pos[n * 3 + 1];
    const float pn2 = (float)pos[n * 3 + 2];

    float runmax[8];
#pragma unroll
    for (int nt = 0; nt < 8; ++nt) runmax[nt] = -3.4e38f;

    for (int c = s; c < e; c += 16) {
      const int idx = min(c + m15, e - 1);      // pad = duplicate last edge
      const int row = srow[idx];
      const float p0 = (float)pos[row * 3 + 0] - pn0;
      const float p1 = (float)pos[row * 3 + 1] - pn1;
      const float p2 = (float)pos[row * 3 + 2] - pn2;
      const bf16_t* xrow = xw1b + (long)row * 128;

      bf16x8 a[4];
#pragma unroll
      for (int kt = 0; kt < 4; ++kt) {
        const int j0 = kt * 32 + quad * 8;
        bf16x8 xv = *(const bf16x8*)(xrow + j0);
        bf16x8 av;
#pragma unroll
        for (int j = 0; j < 8; ++j) {
          float h = (float)xv[j] + p0 * w1ps[0][j0 + j] + p1 * w1ps[1][j0 + j] + p2 * w1ps[2][j0 + j];
          av[j] = (bf16_t)fmaxf(h, 0.f);
        }
        a[kt] = av;
      }

      f32x4 acc[8];
#pragma unroll
      for (int nt = 0; nt < 8; ++nt) acc[nt] = (f32x4){0.f, 0.f, 0.f, 0.f};
#pragma unroll
      for (int nt = 0; nt < 8; ++nt)
#pragma unroll
        for (int kt = 0; kt < 4; ++kt)
          acc[nt] = __builtin_amdgcn_mfma_f32_16x16x32_bf16(
              a[kt], *(const bf16x8*)&w2s[nt][kt][lane][0], acc[nt], 0, 0, 0);

#pragma unroll
      for (int nt = 0; nt < 8; ++nt)
#pragma unroll
        for (int r = 0; r < 4; ++r)
          runmax[nt] = fmaxf(runmax[nt], acc[nt][r]);
    }

    // cross-quad reduction: D rows live on (quad, r); cols on m15 x nt
#pragma unroll
    for (int nt = 0; nt < 8; ++nt) {
      float v = runmax[nt];
      v = fmaxf(v, __shfl_xor(v, 16, 64));
      v = fmaxf(v, __shfl_xor(v, 32, 64));
      v += biasv[nt];
      if (quad == 0) maxbf[(long)n * 128 + nt * 16 + m15] = (bf16_t)v;
    }
  }
}

extern "C" void kernel_launch(void* const* d_in, const int* in_sizes, int n_in,
                              void* d_out, int out_size, void* d_ws, size_t ws_size,
                              hipStream_t stream) {
  (void)n_in; (void)ws_size; (void)out_size;
  const void* x   = d_in[0];
  const void* pos = d_in[1];
  const int*  eix = (const int*)d_in[2];
  const void* W1  = d_in[3];  // 131 x 128; rows 0..127 = W1x, 128..130 = W1p
  const void* b1  = d_in[4];
  const void* W2  = d_in[5];
  const void* b2  = d_in[6];
  const void* Wr  = d_in[7];
  const void* br  = d_in[8];

  const int N = in_sizes[0] / 128;
  const int E = in_sizes[2] / 2;

  bf16_t* maxbf  = (bf16_t*)d_ws;
  int*    srow   = (int*)((char*)d_ws + (size_t)N * 256);
  int*    deg    = srow + E;
  int*    start  = deg + N;
  int*    cursor = start + N + 1;
  int*    flag   = cursor + N;
  bf16_t* xw1b   = (bf16_t*)d_out;   // d_out doubles as bf16 scratch until K7

  detect_kernel<<<1, 64, 0, stream>>>((const unsigned*)x, flag);
  zero_kernel<<<(N + 255) / 256, 256, 0, stream>>>(deg, N);
  hist_kernel<<<(E + 255) / 256, 256, 0, stream>>>(eix, deg, E);
  scan_kernel<<<1, 1024, 0, stream>>>(deg, start, cursor, N);
  scatter_kernel<<<(E + 255) / 256, 256, 0, stream>>>(eix, cursor, srow, E);

  const int nodeBlocks = (N + 63) / 64;
  node_gemm_kernel<bf16_t, false><<<nodeBlocks, 256, 0, stream>>>(
      (const bf16_t*)x, (const bf16_t*)W1, (const bf16_t*)b1, nullptr, xw1b, flag, N);
  node_gemm_kernel<float, false><<<nodeBlocks, 256, 0, stream>>>(
      (const float*)x, (const float*)W1, (const float*)b1, nullptr, xw1b, flag, N);

  pernode_kernel<bf16_t><<<2048, 256, 0, stream>>>(
      (const bf16_t*)pos, xw1b, (const bf16_t*)W1, (const bf16_t*)W2,
      (const bf16_t*)b2, start, srow, maxbf, flag, N);
  pernode_kernel<float><<<2048, 256, 0, stream>>>(
      (const float*)pos, xw1b, (const float*)W1, (const float*)W2,
      (const float*)b2, start, srow, maxbf, flag, N);

  node_gemm_kernel<bf16_t, true><<<nodeBlocks, 256, 0, stream>>>(
      (const bf16_t*)x, (const bf16_t*)Wr, (const bf16_t*)br, maxbf, d_out, flag, N);
  node_gemm_kernel<float, true><<<nodeBlocks, 256, 0, stream>>>(
      (const float*)x, (const float*)Wr, (const float*)br, maxbf, d_out, flag, N);
}